// Round 1
// baseline (675.846 us; speedup 1.0000x reference)
//
#include <hip/hip_runtime.h>
#include <hip/hip_bf16.h>

// BranchingQNetwork fused forward for MI355X (gfx950).
// B=32, N=2048, OBS=256, HID=128, n1=n2=8.

typedef __attribute__((ext_vector_type(4))) float f32x4;
typedef __attribute__((ext_vector_type(8))) short bf16x8;

#define LOG2E 1.44269504088896340736f
#define NEGC 9.0e15f

static __device__ __forceinline__ unsigned short f2bf(float f) {
  unsigned int x = __builtin_bit_cast(unsigned int, f);
  unsigned int r = (x + 0x7fffu + ((x >> 16) & 1u)) >> 16;   // RNE
  return (unsigned short)r;
}
static __device__ __forceinline__ float bf2f(unsigned short u) {
  return __builtin_bit_cast(float, ((unsigned int)u) << 16);
}
static __device__ __forceinline__ f32x4 mfma16(bf16x8 a, bf16x8 b, f32x4 c) {
  return __builtin_amdgcn_mfma_f32_16x16x32_bf16(a, b, c, 0, 0, 0);
}

// ---------------------------------------------------------------------------
// Kernel 0: weight prep. WT (384 cols = [q|k|v]) transposed to [col][256] bf16
// hi/lo split; WoutT transposed to [col][128] bf16.
// ---------------------------------------------------------------------------
__global__ void prep_kernel(const float* __restrict__ Wv, const float* __restrict__ Wk,
                            const float* __restrict__ Wq, const float* __restrict__ Wout,
                            unsigned short* __restrict__ WT_hi, unsigned short* __restrict__ WT_lo,
                            unsigned short* __restrict__ WoutT) {
  int idx = blockIdx.x * 256 + threadIdx.x;
  if (idx < 384 * 256) {
    int j = idx >> 8;      // output col 0..383  (0..127=q, 128..255=k, 256..383=v)
    int c = idx & 255;     // k index
    const float* W = (j < 128) ? Wq : (j < 256) ? Wk : Wv;
    float w = W[c * 128 + (j & 127)];
    unsigned short hi = f2bf(w);
    WT_hi[idx] = hi;
    WT_lo[idx] = f2bf(w - bf2f(hi));
  } else {
    int i2 = idx - 384 * 256;
    if (i2 < 128 * 128) {
      int j = i2 >> 7, c = i2 & 127;
      WoutT[i2] = f2bf(Wout[c * 128 + j]);
    }
  }
}

// ---------------------------------------------------------------------------
// Kernel 1: fused QKV projection. 64 rows/block, 4 waves x 16 rows x 384 cols.
// 3-pass hi/lo split MFMA (near-fp32 result), relu+bias, then:
//   q -> single bf16 ; k -> hi/lo bf16 ; v -> single bf16.
// ---------------------------------------------------------------------------
__global__ __launch_bounds__(256) void proj_kernel(
    const float* __restrict__ x,
    const unsigned short* __restrict__ WT_hi, const unsigned short* __restrict__ WT_lo,
    const float* __restrict__ bq, const float* __restrict__ bk, const float* __restrict__ bv,
    unsigned short* __restrict__ q_bf, unsigned short* __restrict__ k_hi,
    unsigned short* __restrict__ k_lo, unsigned short* __restrict__ v_bf) {
  const int lane = threadIdx.x & 63, wid = threadIdx.x >> 6;
  const int qq = lane >> 4, hh = lane & 15;
  const long rowA = (long)blockIdx.x * 64 + wid * 16 + hh;  // A-frag row
  const f32x4 zero4 = {0.f, 0.f, 0.f, 0.f};
  f32x4 acc[24];
#pragma unroll
  for (int t = 0; t < 24; ++t) acc[t] = zero4;

  for (int kc = 0; kc < 8; ++kc) {
    const float* xp = x + rowA * 256 + kc * 32 + qq * 8;
    f32x4 x0 = *(const f32x4*)xp;
    f32x4 x1 = *(const f32x4*)(xp + 4);
    bf16x8 ah, al;
#pragma unroll
    for (int j = 0; j < 8; ++j) {
      float f = (j < 4) ? x0[j] : x1[j - 4];
      unsigned short h = f2bf(f);
      ah[j] = (short)h;
      al[j] = (short)f2bf(f - bf2f(h));
    }
#pragma unroll
    for (int t = 0; t < 24; ++t) {
      const unsigned short* wp = WT_hi + (t * 16 + hh) * 256 + kc * 32 + qq * 8;
      const unsigned short* wl = WT_lo + (t * 16 + hh) * 256 + kc * 32 + qq * 8;
      bf16x8 bh = *(const bf16x8*)wp;
      bf16x8 bl = *(const bf16x8*)wl;
      acc[t] = mfma16(ah, bh, acc[t]);
      acc[t] = mfma16(al, bh, acc[t]);
      acc[t] = mfma16(ah, bl, acc[t]);
    }
  }
  const long rowC = (long)blockIdx.x * 64 + wid * 16 + qq * 4;
#pragma unroll
  for (int t = 0; t < 24; ++t) {
    const int col = t * 16 + hh;
    const int sec = t >> 3;        // 0=q 1=k 2=v (uniform per t)
    const int j = col & 127;
    const float bias = (sec == 0) ? bq[j] : (sec == 1) ? bk[j] : bv[j];
#pragma unroll
    for (int r = 0; r < 4; ++r) {
      float val = fmaxf(acc[t][r] + bias, 0.f);
      long o = (rowC + r) * 128 + j;
      if (sec == 0) {
        q_bf[o] = f2bf(val);
      } else if (sec == 1) {
        unsigned short h = f2bf(val);
        k_hi[o] = h;
        k_lo[o] = f2bf(val - bf2f(h));
      } else {
        v_bf[o] = f2bf(val);
      }
    }
  }
}

// ---------------------------------------------------------------------------
// Kernel 2: flash attention with multiplicative mask.
// Grid: 256 blocks (b = idx>>3, row block = (idx&7)*256). 8 waves x 32 rows.
// KVBLK=64, double-buffered LDS; K tiles XOR-swizzled; V stored transposed in
// LDS [h][m] (stride 72); per-wave P transpose buffer (stride 72).
// QK^T = 2-pass (q_bf x (k_hi + k_lo)); softmax fp32 online; PV 1-pass.
// ---------------------------------------------------------------------------
__global__ __launch_bounds__(512) void attn_kernel(
    const unsigned short* __restrict__ q_bf, const unsigned short* __restrict__ k_hi,
    const unsigned short* __restrict__ k_lo, const unsigned short* __restrict__ v_bf,
    const float* __restrict__ mask, unsigned short* __restrict__ out_att) {
  __shared__ unsigned short kh_lds[2][64 * 128];
  __shared__ unsigned short kl_lds[2][64 * 128];
  __shared__ unsigned short vt_lds[2][128 * 72];
  __shared__ unsigned short p_lds[8][32 * 72];

  const int tid = threadIdx.x;
  const int lane = tid & 63, wid = tid >> 6;
  const int qq = lane >> 4, hh = lane & 15;
  const int b = blockIdx.x >> 3;
  const int n0 = (blockIdx.x & 7) << 8;
  const long bn = (long)b * 2048;
  const long qrow0 = bn + n0 + wid * 32;
  const f32x4 zero4 = {0.f, 0.f, 0.f, 0.f};

  // hoisted Q fragments (rows qrow0 + rt*16 + hh, k chunk kc*32 + qq*8)
  bf16x8 qh[2][4];
#pragma unroll
  for (int rt = 0; rt < 2; ++rt)
#pragma unroll
    for (int kc = 0; kc < 4; ++kc)
      qh[rt][kc] = *(const bf16x8*)(q_bf + (qrow0 + rt * 16 + hh) * 128 + kc * 32 + qq * 8);

  f32x4 o_acc[2][8];
#pragma unroll
  for (int rt = 0; rt < 2; ++rt)
#pragma unroll
    for (int ht = 0; ht < 8; ++ht) o_acc[rt][ht] = zero4;
  float m_run[2][4], l_run[2][4];
#pragma unroll
  for (int rt = 0; rt < 2; ++rt)
#pragma unroll
    for (int r = 0; r < 4; ++r) { m_run[rt][r] = -3.0e38f; l_run[rt][r] = 0.f; }

  const int vm = lane;          // V staging: row within tile
  const int vc8 = wid * 2;      // V staging: 8-col chunk base

  f32x4 stg[6];
  auto LOAD = [&](int tt) {
    const unsigned short* khp = k_hi + (bn + tt * 64) * 128;
    const unsigned short* klp = k_lo + (bn + tt * 64) * 128;
    const unsigned short* vp  = v_bf + (bn + tt * 64) * 128;
    stg[0] = *(const f32x4*)((const char*)khp + tid * 16);
    stg[1] = *(const f32x4*)((const char*)khp + tid * 16 + 8192);
    stg[2] = *(const f32x4*)((const char*)klp + tid * 16);
    stg[3] = *(const f32x4*)((const char*)klp + tid * 16 + 8192);
    stg[4] = *(const f32x4*)(vp + (long)vm * 128 + vc8 * 8);
    stg[5] = *(const f32x4*)(vp + (long)vm * 128 + (vc8 + 1) * 8);
  };
  auto STORE = [&](int nb) {
#pragma unroll
    for (int i = 0; i < 2; ++i) {
      int c = tid + i * 512;
      int m = c >> 4;
      int bcol = (c & 15) << 4;
      int addr = m * 256 + (bcol ^ ((m & 7) << 4));   // XOR swizzle, keeps 16B align
      *(f32x4*)((char*)kh_lds[nb] + addr) = stg[i];
      *(f32x4*)((char*)kl_lds[nb] + addr) = stg[2 + i];
    }
#pragma unroll
    for (int i = 0; i < 2; ++i) {
      bf16x8 sv = __builtin_bit_cast(bf16x8, stg[4 + i]);
#pragma unroll
      for (int j = 0; j < 8; ++j)
        vt_lds[nb][((vc8 + i) * 8 + j) * 72 + vm] = (unsigned short)sv[j];  // transpose
    }
  };

  LOAD(0);
  STORE(0);
  LOAD(1);
  __syncthreads();

  for (int t = 0; t < 32; ++t) {
    const int cur = t & 1;
    const int kb = t << 6;
    if (t + 1 < 32) STORE(cur ^ 1);
    if (t + 2 < 32) LOAD(t + 2);

    // mask loads (fragment layout: row = qq*4+r within rt-tile, col = ct*16+hh)
    float mreg[2][4][4];
#pragma unroll
    for (int rt = 0; rt < 2; ++rt)
#pragma unroll
      for (int r = 0; r < 4; ++r) {
        const float* mp = mask + (bn + n0 + wid * 32 + rt * 16 + qq * 4 + r) * 2048 + kb + hh;
#pragma unroll
        for (int ct = 0; ct < 4; ++ct) mreg[rt][ct][r] = mp[ct * 16];
      }

    // S = Q K^T (2-pass: hi + lo K)
    f32x4 s_acc[2][4];
#pragma unroll
    for (int rt = 0; rt < 2; ++rt)
#pragma unroll
      for (int ct = 0; ct < 4; ++ct) s_acc[rt][ct] = zero4;
#pragma unroll
    for (int ct = 0; ct < 4; ++ct) {
      const int m = ct * 16 + hh;
      const int rowoff = m << 8;
      const int swz = (m & 7) << 4;
#pragma unroll
      for (int kc = 0; kc < 4; ++kc) {
        const int boff = (kc * 32 + qq * 8) << 1;
        const int addr = rowoff + (boff ^ swz);
        bf16x8 khf = *(const bf16x8*)((const char*)kh_lds[cur] + addr);
        bf16x8 klf = *(const bf16x8*)((const char*)kl_lds[cur] + addr);
#pragma unroll
        for (int rt = 0; rt < 2; ++rt) {
          s_acc[rt][ct] = mfma16(qh[rt][kc], khf, s_acc[rt][ct]);
          s_acc[rt][ct] = mfma16(qh[rt][kc], klf, s_acc[rt][ct]);
        }
      }
    }

    // mask + fp32 online softmax
#pragma unroll
    for (int rt = 0; rt < 2; ++rt)
#pragma unroll
      for (int r = 0; r < 4; ++r) {
        float mx = -3.0e38f;
#pragma unroll
        for (int ct = 0; ct < 4; ++ct) {
          float mv = mreg[rt][ct][r];
          float s = mv * s_acc[rt][ct][r] - NEGC * (1.0f - mv);
          s_acc[rt][ct][r] = s;
          mx = fmaxf(mx, s);
        }
        mx = fmaxf(mx, __shfl_xor(mx, 1, 64));
        mx = fmaxf(mx, __shfl_xor(mx, 2, 64));
        mx = fmaxf(mx, __shfl_xor(mx, 4, 64));
        mx = fmaxf(mx, __shfl_xor(mx, 8, 64));
        float mnew = fmaxf(m_run[rt][r], mx);
        float scale = exp2f((m_run[rt][r] - mnew) * LOG2E);
        m_run[rt][r] = mnew;
        float ps = 0.f;
#pragma unroll
        for (int ct = 0; ct < 4; ++ct) {
          float p = exp2f((s_acc[rt][ct][r] - mnew) * LOG2E);
          s_acc[rt][ct][r] = p;
          ps += p;
        }
        ps += __shfl_xor(ps, 1, 64);
        ps += __shfl_xor(ps, 2, 64);
        ps += __shfl_xor(ps, 4, 64);
        ps += __shfl_xor(ps, 8, 64);
        l_run[rt][r] = l_run[rt][r] * scale + ps;
#pragma unroll
        for (int ht = 0; ht < 8; ++ht) o_acc[rt][ht][r] *= scale;
      }

    // P -> per-wave LDS (C-layout -> A-frag layout transpose)
    unsigned short* pl = p_lds[wid];
#pragma unroll
    for (int rt = 0; rt < 2; ++rt)
#pragma unroll
      for (int ct = 0; ct < 4; ++ct)
#pragma unroll
        for (int r = 0; r < 4; ++r)
          pl[(rt * 16 + qq * 4 + r) * 72 + ct * 16 + hh] = f2bf(s_acc[rt][ct][r]);

    bf16x8 paf[2][2];
#pragma unroll
    for (int rt = 0; rt < 2; ++rt)
#pragma unroll
      for (int mc = 0; mc < 2; ++mc)
        paf[rt][mc] = *(const bf16x8*)(pl + (rt * 16 + hh) * 72 + mc * 32 + qq * 8);

    // O += P V
#pragma unroll
    for (int ht = 0; ht < 8; ++ht)
#pragma unroll
      for (int mc = 0; mc < 2; ++mc) {
        bf16x8 vf = *(const bf16x8*)(&vt_lds[cur][(ht * 16 + hh) * 72 + mc * 32 + qq * 8]);
#pragma unroll
        for (int rt = 0; rt < 2; ++rt)
          o_acc[rt][ht] = mfma16(paf[rt][mc], vf, o_acc[rt][ht]);
      }
    __syncthreads();
  }

  // epilogue: normalize and store bf16
#pragma unroll
  for (int rt = 0; rt < 2; ++rt)
#pragma unroll
    for (int r = 0; r < 4; ++r) {
      float inv = 1.0f / l_run[rt][r];
      const long row = qrow0 + rt * 16 + qq * 4 + r;
#pragma unroll
      for (int ht = 0; ht < 8; ++ht)
        out_att[row * 128 + ht * 16 + hh] = f2bf(o_acc[rt][ht][r] * inv);
    }
}

// ---------------------------------------------------------------------------
// Kernel 3: out = relu(out_att @ Wout + bout) fused with the three heads.
// h never leaves registers (full fp32 head dots). 64 rows/block, 4 waves.
// ---------------------------------------------------------------------------
__global__ __launch_bounds__(256) void wout_heads_kernel(
    const unsigned short* __restrict__ out_att, const unsigned short* __restrict__ WoutT,
    const float* __restrict__ bout,
    const float* __restrict__ Wval, const float* __restrict__ bval,
    const float* __restrict__ Wadv1, const float* __restrict__ badv1,
    const float* __restrict__ Wadv2, const float* __restrict__ badv2,
    float* __restrict__ value, float* __restrict__ adv1, float* __restrict__ adv2) {
  const int lane = threadIdx.x & 63, wid = threadIdx.x >> 6;
  const int qq = lane >> 4, hh = lane & 15;
  const long rowA = (long)blockIdx.x * 64 + wid * 16 + hh;
  const f32x4 zero4 = {0.f, 0.f, 0.f, 0.f};
  f32x4 acc[8];
#pragma unroll
  for (int t = 0; t < 8; ++t) acc[t] = zero4;
#pragma unroll
  for (int kc = 0; kc < 4; ++kc) {
    bf16x8 af = *(const bf16x8*)(out_att + rowA * 128 + kc * 32 + qq * 8);
#pragma unroll
    for (int t = 0; t < 8; ++t) {
      bf16x8 bf = *(const bf16x8*)(WoutT + (t * 16 + hh) * 128 + kc * 32 + qq * 8);
      acc[t] = mfma16(af, bf, acc[t]);
    }
  }
  float pv[4] = {0.f, 0.f, 0.f, 0.f};
  float pa1[4][8], pa2[4][8];
#pragma unroll
  for (int r = 0; r < 4; ++r)
#pragma unroll
    for (int j = 0; j < 8; ++j) { pa1[r][j] = 0.f; pa2[r][j] = 0.f; }
#pragma unroll
  for (int t = 0; t < 8; ++t) {
    const int col = t * 16 + hh;
    const float bo = bout[col];
    const float wv = Wval[col];
    const f32x4 w1a = *(const f32x4*)(Wadv1 + col * 8);
    const f32x4 w1b = *(const f32x4*)(Wadv1 + col * 8 + 4);
    const f32x4 w2a = *(const f32x4*)(Wadv2 + col * 8);
    const f32x4 w2b = *(const f32x4*)(Wadv2 + col * 8 + 4);
#pragma unroll
    for (int r = 0; r < 4; ++r) {
      float h = fmaxf(acc[t][r] + bo, 0.f);
      pv[r] += h * wv;
#pragma unroll
      for (int j = 0; j < 4; ++j) {
        pa1[r][j]     += h * w1a[j];
        pa1[r][4 + j] += h * w1b[j];
        pa2[r][j]     += h * w2a[j];
        pa2[r][4 + j] += h * w2b[j];
      }
    }
  }
#pragma unroll
  for (int r = 0; r < 4; ++r) {
#pragma unroll
    for (int s = 1; s < 16; s <<= 1) {
      pv[r] += __shfl_xor(pv[r], s, 64);
#pragma unroll
      for (int j = 0; j < 8; ++j) {
        pa1[r][j] += __shfl_xor(pa1[r][j], s, 64);
        pa2[r][j] += __shfl_xor(pa2[r][j], s, 64);
      }
    }
  }
  if (hh == 0) {
    const float bv0 = bval[0];
#pragma unroll
    for (int r = 0; r < 4; ++r) {
      const long row = (long)blockIdx.x * 64 + wid * 16 + qq * 4 + r;
      value[row] = pv[r] + bv0;
#pragma unroll
      for (int j = 0; j < 8; ++j) {
        adv1[row * 8 + j] = pa1[r][j] + badv1[j];
        adv2[row * 8 + j] = pa2[r][j] + badv2[j];
      }
    }
  }
}

// ---------------------------------------------------------------------------
// Kernel 4: per-batch column sums of adv1/adv2 over N (deterministic tree).
// One block per batch; sums[b*16 + 0..7] = sum adv1, [8..15] = sum adv2.
// ---------------------------------------------------------------------------
__global__ __launch_bounds__(256) void sums_kernel(const float* __restrict__ adv1,
                                                   const float* __restrict__ adv2,
                                                   float* __restrict__ sums) {
  const int b = blockIdx.x, tid = threadIdx.x;
  __shared__ float red[4][16];
  float p[16];
#pragma unroll
  for (int j = 0; j < 16; ++j) p[j] = 0.f;
  for (int n = tid; n < 2048; n += 256) {
    const long row = (long)b * 2048 + n;
    const f32x4 a1a = *(const f32x4*)(adv1 + row * 8);
    const f32x4 a1b = *(const f32x4*)(adv1 + row * 8 + 4);
    const f32x4 a2a = *(const f32x4*)(adv2 + row * 8);
    const f32x4 a2b = *(const f32x4*)(adv2 + row * 8 + 4);
#pragma unroll
    for (int j = 0; j < 4; ++j) {
      p[j] += a1a[j]; p[4 + j] += a1b[j];
      p[8 + j] += a2a[j]; p[12 + j] += a2b[j];
    }
  }
#pragma unroll
  for (int s = 1; s < 64; s <<= 1)
#pragma unroll
    for (int j = 0; j < 16; ++j) p[j] += __shfl_xor(p[j], s, 64);
  const int wid = tid >> 6;
  if ((tid & 63) == 0)
#pragma unroll
    for (int j = 0; j < 16; ++j) red[wid][j] = p[j];
  __syncthreads();
  if (tid < 16)
    sums[b * 16 + tid] = red[0][tid] + red[1][tid] + red[2][tid] + red[3][tid];
}

// ---------------------------------------------------------------------------
// Kernel 5: q1/q2 = value + adv - mean(adv). Output: [q1 | q2] fp32 flat.
// ---------------------------------------------------------------------------
__global__ void combine_kernel(const float* __restrict__ value, const float* __restrict__ adv1,
                               const float* __restrict__ adv2, const float* __restrict__ sums,
                               float* __restrict__ out) {
  const int idx = blockIdx.x * 256 + threadIdx.x;   // 0 .. 1048575
  const int half = 524288;
  const int which = (idx >= half) ? 1 : 0;
  const int rem = idx - which * half;
  const int b = rem >> 14;
  const int r2 = rem & 16383;
  const int n = r2 >> 3, j = r2 & 7;
  const long row = (long)b * 2048 + n;
  const float* adv = which ? adv2 : adv1;
  const float mean = sums[b * 16 + which * 8 + j] * (1.0f / 2048.0f);
  out[idx] = value[row] + adv[row * 8 + j] - mean;
}

// ---------------------------------------------------------------------------
extern "C" void kernel_launch(void* const* d_in, const int* in_sizes, int n_in,
                              void* d_out, int out_size, void* d_ws, size_t ws_size,
                              hipStream_t stream) {
  const float* x     = (const float*)d_in[0];
  const float* mask  = (const float*)d_in[1];
  const float* Wv    = (const float*)d_in[2];
  const float* bv    = (const float*)d_in[3];
  const float* Wk    = (const float*)d_in[4];
  const float* bk    = (const float*)d_in[5];
  const float* Wq    = (const float*)d_in[6];
  const float* bq    = (const float*)d_in[7];
  const float* Wout  = (const float*)d_in[8];
  const float* bout  = (const float*)d_in[9];
  const float* Wval  = (const float*)d_in[10];
  const float* bval  = (const float*)d_in[11];
  const float* Wadv1 = (const float*)d_in[12];
  const float* badv1 = (const float*)d_in[13];
  const float* Wadv2 = (const float*)d_in[14];
  const float* badv2 = (const float*)d_in[15];
  float* out = (float*)d_out;
  char* ws = (char*)d_ws;

  // workspace layout (bytes)
  unsigned short* q_bf   = (unsigned short*)(ws + 0);
  unsigned short* k_hi   = (unsigned short*)(ws + 16777216);
  unsigned short* k_lo   = (unsigned short*)(ws + 33554432);
  unsigned short* v_bf   = (unsigned short*)(ws + 50331648);
  unsigned short* out_at = (unsigned short*)(ws + 67108864);
  float* value = (float*)(ws + 83886080);
  float* adv1  = (float*)(ws + 84148224);
  float* adv2  = (float*)(ws + 86245376);
  float* sums  = (float*)(ws + 88342528);
  unsigned short* WT_hi = (unsigned short*)(ws + 88344576);
  unsigned short* WT_lo = (unsigned short*)(ws + 88541184);
  unsigned short* WoutT = (unsigned short*)(ws + 88737792);

  prep_kernel<<<448, 256, 0, stream>>>(Wv, Wk, Wq, Wout, WT_hi, WT_lo, WoutT);
  proj_kernel<<<1024, 256, 0, stream>>>(x, WT_hi, WT_lo, bq, bk, bv,
                                        q_bf, k_hi, k_lo, v_bf);
  attn_kernel<<<256, 512, 0, stream>>>(q_bf, k_hi, k_lo, v_bf, mask, out_at);
  wout_heads_kernel<<<1024, 256, 0, stream>>>(out_at, WoutT, bout, Wval, bval,
                                              Wadv1, badv1, Wadv2, badv2,
                                              value, adv1, adv2);
  sums_kernel<<<32, 256, 0, stream>>>(adv1, adv2, sums);
  combine_kernel<<<4096, 256, 0, stream>>>(value, adv1, adv2, sums, out);
}